// Round 13
// baseline (267.903 us; speedup 1.0000x reference)
//
#include <hip/hip_runtime.h>
#include <hip/hip_bf16.h>
#include <stdint.h>

// ---- problem constants ----
#define BATCH 4
#define SEQ   8400
#define DM    512
#define KP    8484      // SEQ + 2*42 (edge pad)
#define NWIN  100
#define STEP_ 84
#define PAD_  42
#define NKEY  126
#define MROWS 33600     // BATCH*SEQ
#define NTILES 266      // ceil(KP/32)
#define TPB   13        // tiles per work unit (21*13 >= 266)
#define NBI   21
#define OT_TPB 3        // kout tiles per work unit (350*3 = 1050 exact)
#define OT_NBI 350

typedef __attribute__((ext_vector_type(8))) short short8;
typedef __attribute__((ext_vector_type(4))) float float4v;
typedef __attribute__((ext_vector_type(4))) unsigned short ushort4v;

#define MFMA16 __builtin_amdgcn_mfma_f32_16x16x32_bf16

__device__ __forceinline__ unsigned short f2bf(float f) {
    union { float f; unsigned u; } v; v.f = f;
    return (unsigned short)((v.u + 0x7FFFu + ((v.u >> 16) & 1u)) >> 16);  // RNE
}
__device__ __forceinline__ unsigned short bfc(float f) {
    __hip_bfloat16 h = __float2bfloat16(f);
    union { __hip_bfloat16 h; unsigned short u; } v; v.h = h;
    return v.u;
}

typedef __attribute__((address_space(1))) const unsigned int as1_cu32;
typedef __attribute__((address_space(3))) unsigned int as3_u32;
__device__ __forceinline__ void gload16(const void* g, void* l) {
    __builtin_amdgcn_global_load_lds((as1_cu32*)g, (as3_u32*)l, 16, 0, 0);
}

// ============ prepass: W (f32 [k][n] 512x512) -> Wt (bf16 [n][k]) ============
__global__ __launch_bounds__(256) void kprep(const float* __restrict__ Wq,
                                             const float* __restrict__ Wk,
                                             const float* __restrict__ Wv,
                                             const float* __restrict__ Wo,
                                             unsigned short* __restrict__ Wt) {
    const float* src = blockIdx.z == 0 ? Wq : blockIdx.z == 1 ? Wk
                     : blockIdx.z == 2 ? Wv : Wo;
    unsigned short* dst = Wt + (size_t)blockIdx.z * DM * DM;
    __shared__ float t[64][65];
    int c = threadIdx.x & 63, r4 = threadIdx.x >> 6;
    int kb = blockIdx.x * 64, nb = blockIdx.y * 64;
    for (int i = 0; i < 16; i++) {
        int r = r4 * 16 + i;
        t[r][c] = src[(size_t)(kb + r) * DM + nb + c];
    }
    __syncthreads();
    for (int i = 0; i < 16; i++) {
        int r = r4 * 16 + i;
        dst[(size_t)(nb + r) * DM + kb + c] = f2bf(t[c][r]);
    }
}

// ============ kernel 1: weight-stationary fused pad+cvt+QKV projection =======
// R13: wave owns 16 n-cols (Breg = 64 regs) so total regs fit 128 ->
// 2 blocks/CU (16 waves). 8-wave block covers 128 n; A read 4x (L2-absorbed).
// A tile [32 m][512 k]: f32 reg-prefetch -> cvt -> swizzled LDS (32 KB,
// single buffer, 2 barriers/tile — R11 proven loop).
// Grid 1024 (pad): the 4 n-groups of one work unit are 8/16/24 apart -> same
// XCD under round-robin -> shared-A L2 hits.
__global__ __launch_bounds__(512, 4) void kproj(const float* __restrict__ q,
                                                const float* __restrict__ k,
                                                const float* __restrict__ v,
                                                const unsigned short* __restrict__ Wt,
                                                const float* __restrict__ bq,
                                                const float* __restrict__ bk,
                                                const float* __restrict__ bv,
                                                unsigned short* __restrict__ Qb,
                                                unsigned short* __restrict__ Kb,
                                                unsigned short* __restrict__ VT) {
    int L = blockIdx.x;                          // 0..1023 (1008 active)
    int P = (L >> 5) * 8 + (L & 7);              // work unit 0..255
    int ngroup = (L >> 3) & 3;                   // n-quarter
    if (P >= 12 * NBI) return;
    int z = P / NBI, bi = P % NBI;
    int ten = z >> 2, b = z & 3;
    int t0 = bi * TPB;
    int tcnt = NTILES - t0; if (tcnt > TPB) tcnt = TPB;
    if (tcnt <= 0) return;

    const float* A = (ten == 0 ? q : ten == 1 ? k : v) + (size_t)b * SEQ * DM;
    const unsigned short* Wten = Wt + (size_t)ten * DM * DM;
    const float* bias = ten == 0 ? bq : ten == 1 ? bk : bv;
    float scale = ten == 0 ? 0.07715167498104595f : 1.f;   // 1/sqrt(168)

    __shared__ __align__(16) char lds[32768];    // [32 rows][1024 B] bf16 swz

    int tid = threadIdx.x, lane = tid & 63, w = tid >> 6;
    int l15 = lane & 15, g = lane >> 4;
    int n0w = ngroup * 128 + w * 16;             // wave's 16-col slice
    int h = n0w >> 6;
    int hb2 = h * BATCH + b;

    // ---- B slice into registers (once per block): 16 short8 = 64 regs
    short8 Breg[16];
#pragma unroll
    for (int s5 = 0; s5 < 16; s5++)
        Breg[s5] = *(const short8*)(Wten +
            (size_t)(n0w + l15) * DM + s5 * 32 + g * 8);

    float bias0 = bias[n0w + l15];

    int srow = tid >> 4, sc = tid & 15;
    int woff = srow * 1024 + ((sc ^ (srow & 7)) << 4);

    auto loadreg = [&](float4v (&d)[8], int tt) {
        int p = tt * 32 + srow; if (p > KP - 1) p = KP - 1;
        int ar = p - PAD_; ar = ar < 0 ? 0 : (ar > SEQ - 1 ? SEQ - 1 : ar);
        const float* s = A + (size_t)ar * DM + sc * 8;
#pragma unroll
        for (int j = 0; j < 4; j++) {
            d[2 * j]     = *(const float4v*)(s + j * 128);
            d[2 * j + 1] = *(const float4v*)(s + j * 128 + 4);
        }
    };

    float4v a[8];
    loadreg(a, t0);

    for (int ti = 0; ti < tcnt; ti++) {
        int tt = t0 + ti;
#pragma unroll
        for (int j = 0; j < 4; j++) {
            float4v f0 = a[2 * j], f1 = a[2 * j + 1];
            short8 h0;
            h0[0] = (short)bfc(f0.x); h0[1] = (short)bfc(f0.y);
            h0[2] = (short)bfc(f0.z); h0[3] = (short)bfc(f0.w);
            h0[4] = (short)bfc(f1.x); h0[5] = (short)bfc(f1.y);
            h0[6] = (short)bfc(f1.z); h0[7] = (short)bfc(f1.w);
            *(short8*)(lds + woff + j * 256) = h0;
        }
        if (ti + 1 < tcnt) loadreg(a, tt + 1);
        __builtin_amdgcn_sched_barrier(0);
        asm volatile("s_waitcnt lgkmcnt(0)" ::: "memory");
        __builtin_amdgcn_s_barrier();
        __builtin_amdgcn_sched_barrier(0);

        float4v acc[2];
#pragma unroll
        for (int mf = 0; mf < 2; mf++) {
            float4v zz = {0.f, 0.f, 0.f, 0.f}; acc[mf] = zz;
        }
#pragma unroll
        for (int s5 = 0; s5 < 16; s5++) {
            short8 afr[2];
#pragma unroll
            for (int mf = 0; mf < 2; mf++) {
                int row = mf * 16 + l15, c = s5 * 4 + g;
                afr[mf] = *(const short8*)(lds + row * 1024 + ((c ^ (row & 7)) << 4));
            }
#pragma unroll
            for (int mf = 0; mf < 2; mf++)
                acc[mf] = MFMA16(afr[mf], Breg[s5], acc[mf], 0, 0, 0);
        }
        __builtin_amdgcn_s_barrier();            // reads done -> buf reusable
        __builtin_amdgcn_sched_barrier(0);

        int p0 = tt * 32;
        if (ten <= 1) {
            unsigned short* O = ten == 0 ? Qb : Kb;
            int d = (n0w & 63) + l15;
            unsigned short* op = O + (size_t)hb2 * KP * 64 + d;
#pragma unroll
            for (int mf = 0; mf < 2; mf++) {
                float4v vv = acc[mf];
#pragma unroll
                for (int r = 0; r < 4; r++) {
                    int p = p0 + mf * 16 + g * 4 + r;
                    if (p < KP)
                        op[(size_t)p * 64] = f2bf((vv[r] + bias0) * scale);
                }
            }
        } else {
            int d = (n0w & 63) + l15;
            unsigned short* base = VT + ((size_t)hb2 * 64 + d) * KP;
#pragma unroll
            for (int mf = 0; mf < 2; mf++) {
                int p = p0 + mf * 16 + g * 4;
                if (p <= KP - 4) {
                    float4v vv = acc[mf];
                    ushort4v wv;
                    wv[0] = f2bf(vv.x + bias0); wv[1] = f2bf(vv.y + bias0);
                    wv[2] = f2bf(vv.z + bias0); wv[3] = f2bf(vv.w + bias0);
                    *(ushort4v*)(base + p) = wv;
                }
            }
        }
    }
}

// ============ kernel 2: windowed causal attention (44 KB, XCD work remap) ====
__global__ __launch_bounds__(384) void kattn(const unsigned short* __restrict__ Qb,
                                             const unsigned short* __restrict__ Kb,
                                             const unsigned short* __restrict__ VT,
                                             unsigned short* __restrict__ attn) {
    int nid = blockIdx.y * NWIN + blockIdx.x;    // 0..3199
    int work = (nid & 7) * 400 + (nid >> 3);     // bijective (3200 % 8 == 0)
    int win = work % NWIN, hb = work / NWIN;
    int h = hb >> 2, b = hb & 3;
    const unsigned short* Qg = Qb + (size_t)hb * KP * 64;
    const unsigned short* Kg = Kb + (size_t)hb * KP * 64;
    const unsigned short* Vt = VT + (size_t)hb * 64 * KP;
    int p0 = win * STEP_;

    __shared__ __align__(16) char lds[45056];

    int tid = threadIdx.x, lane = tid & 63, f = tid >> 6;
    int l15 = lane & 15, g = lane >> 4;

#pragma unroll
    for (int it = 0; it < 5; it++) {
        int base = it * 384 + f * 64;
        if (base < 768) {                       // Q chunks
            int c = base + lane;
            int qi = c >> 3, kg = (c & 7) ^ (qi & 7);
            gload16(Qg + (size_t)(p0 + PAD_ + qi) * 64 + kg * 8, lds + base * 16);
        } else if (base < 1792) {               // K chunks
            int c = base + lane - 768;
            int x = c >> 3, kg = (c & 7) ^ (x & 7);
            gload16(Kg + (size_t)(p0 + x) * 64 + kg * 8, lds + base * 16);
        }
    }
    for (int c = tid; c < 2048; c += 384) {
        int d = c >> 5, c2 = c & 31;
        ushort4v wv = *(const ushort4v*)(Vt + (size_t)d * KP + p0 + c2 * 4);
        int cx = c2 >> 1;
        *(ushort4v*)(lds + 28672 + d * 256 + (((cx ^ (d & 7)) << 4) | ((c2 & 1) * 8))) = wv;
    }
    __syncthreads();

    short8 bq2[2];
    {
        int r = f * 16 + l15;
#pragma unroll
        for (int ks = 0; ks < 2; ks++) {
            int kg = ks * 4 + g;
            bq2[ks] = *(const short8*)(lds + r * 128 + ((kg ^ (r & 7)) << 4));
        }
    }
    float4v st[8];
#pragma unroll
    for (int xf = 0; xf < 8; xf++) {
        float4v zz = {0.f,0.f,0.f,0.f}; st[xf] = zz;
#pragma unroll
        for (int ks = 0; ks < 2; ks++) {
            int r = xf * 16 + l15;
            int kg = ks * 4 + g;
            short8 a = *(const short8*)(lds + 12288 + r * 128 + ((kg ^ (r & 7)) << 4));
            st[xf] = MFMA16(a, bq2[ks], st[xf], 0, 0, 0);
        }
    }

    int w_abs = PAD_ + f * 16 + l15;
    int w_eff = w_abs > 125 ? 125 : w_abs;
    float mx = -1e30f;
#pragma unroll
    for (int xf = 0; xf < 8; xf++)
#pragma unroll
        for (int r = 0; r < 4; r++) {
            int x = xf * 16 + g * 4 + r;
            float vv = st[xf][r];
            if (x > w_eff) vv = -1e30f;
            st[xf][r] = vv;
            mx = fmaxf(mx, vv);
        }
    mx = fmaxf(mx, __shfl_xor(mx, 16));
    mx = fmaxf(mx, __shfl_xor(mx, 32));
    float s = 0.f;
#pragma unroll
    for (int xf = 0; xf < 8; xf++)
#pragma unroll
        for (int r = 0; r < 4; r++) {
            float e = __expf(st[xf][r] - mx);
            st[xf][r] = e;
            s += e;
        }
    s += __shfl_xor(s, 16);
    s += __shfl_xor(s, 32);
    float inv = 1.f / s;

    __syncthreads();   // Ql/Kl reads done -> Pl may clobber [0,24576)

    {
        int qi = f * 16 + l15;
#pragma unroll
        for (int xf = 0; xf < 8; xf++) {
            ushort4v pw;
#pragma unroll
            for (int r = 0; r < 4; r++) pw[r] = f2bf(st[xf][r] * inv);
            int xc = 2 * xf + (g >> 1);
            *(ushort4v*)(lds + qi * 256 + ((xc ^ (qi & 7)) << 4) + (g & 1) * 8) = pw;
        }
    }
    asm volatile("s_waitcnt lgkmcnt(0)" ::: "memory");
    __builtin_amdgcn_sched_barrier(0);

    float4v pv[4];
#pragma unroll
    for (int j = 0; j < 4; j++) { float4v zz = {0.f,0.f,0.f,0.f}; pv[j] = zz; }
    int qi = f * 16 + l15;
#pragma unroll
    for (int g2 = 0; g2 < 4; g2++) {
        int xc = g2 * 4 + g;
        short8 a = *(const short8*)(lds + qi * 256 + ((xc ^ (qi & 7)) << 4));
#pragma unroll
        for (int j = 0; j < 4; j++) {
            int d = j * 16 + l15;
            short8 bvv = *(const short8*)(lds + 28672 + d * 256 + ((xc ^ (d & 7)) << 4));
            pv[j] = MFMA16(a, bvv, pv[j], 0, 0, 0);
        }
    }

    __syncthreads();   // PV reads of P done -> Ol may clobber [0,12288)

    unsigned short* Ol = (unsigned short*)lds;
#pragma unroll
    for (int j = 0; j < 4; j++) {
        int d = j * 16 + l15;
#pragma unroll
        for (int r = 0; r < 4; r++) {
            int qq = f * 16 + g * 4 + r;
            int byte = qq * 128 + ((((d >> 3) ^ (qq & 7))) << 4) + (d & 7) * 2;
            *(unsigned short*)((char*)Ol + byte) = f2bf(pv[j][r]);
        }
    }
    __syncthreads();
    for (int c = tid; c < 672; c += 384) {
        int qq = c >> 3, ch = c & 7;
        short8 hv = *(const short8*)((char*)Ol + qq * 128 + ((ch ^ (qq & 7)) << 4));
        size_t off = ((size_t)(b * SEQ + win * STEP_ + qq) * DM) + h * 64 + ch * 8;
        *(short8*)(attn + off) = hv;
    }
}

// ============ kernel 3: weight-stationary output projection ==================
__global__ __launch_bounds__(512, 2) void kout(const unsigned short* __restrict__ Ab,
                                               const unsigned short* __restrict__ W,
                                               const float* __restrict__ bias,
                                               float* __restrict__ Out) {
    int L = blockIdx.x;                          // 0..703
    int P = (L >> 4) * 8 + (L & 7);
    int nhalf = (L >> 3) & 1;
    if (P >= OT_NBI) return;
    int t0 = P * OT_TPB;

    __shared__ __align__(16) char lds[32768];

    int tid = threadIdx.x, lane = tid & 63, w = tid >> 6;
    int l15 = lane & 15, g = lane >> 4;
    int n0w = nhalf * 256 + w * 32;

    short8 Breg[2][16];
#pragma unroll
    for (int nf = 0; nf < 2; nf++)
#pragma unroll
        for (int s5 = 0; s5 < 16; s5++)
            Breg[nf][s5] = *(const short8*)(W +
                (size_t)(n0w + nf * 16 + l15) * DM + s5 * 32 + g * 8);

    float bias0 = bias[n0w + l15];
    float bias1 = bias[n0w + 16 + l15];

    int srow = tid >> 4, sc = tid & 15;

    auto loadreg = [&](short8 (&d)[4], int tt) {
        const unsigned short* s = Ab + (size_t)(tt * 32 + srow) * DM;
#pragma unroll
        for (int j = 0; j < 4; j++)
            d[j] = *(const short8*)(s + (sc + j * 16) * 8);
    };

    short8 a[4];
    loadreg(a, t0);

    for (int ti = 0; ti < OT_TPB; ti++) {
        int tt = t0 + ti;
#pragma unroll
        for (int j = 0; j < 4; j++)
            *(short8*)(lds + srow * 1024 +
                       (((sc + j * 16) ^ (srow & 7)) << 4)) = a[j];
        if (ti + 1 < OT_TPB) loadreg(a, tt + 1);
        __builtin_amdgcn_sched_barrier(0);
        asm volatile("s_waitcnt lgkmcnt(0)" ::: "memory");
        __builtin_amdgcn_s_barrier();
        __builtin_amdgcn_sched_barrier(0);

        float4v acc[2][2];
#pragma unroll
        for (int mf = 0; mf < 2; mf++)
#pragma unroll
            for (int nf = 0; nf < 2; nf++) {
                float4v zz = {0.f, 0.f, 0.f, 0.f}; acc[mf][nf] = zz;
            }
#pragma unroll
        for (int s5 = 0; s5 < 16; s5++) {
            short8 afr[2];
#pragma unroll
            for (int mf = 0; mf < 2; mf++) {
                int row = mf * 16 + l15, c = s5 * 4 + g;
                afr[mf] = *(const short8*)(lds + row * 1024 + ((c ^ (row & 7)) << 4));
            }
#pragma unroll
            for (int mf = 0; mf < 2; mf++)
#pragma unroll
                for (int nf = 0; nf < 2; nf++)
                    acc[mf][nf] = MFMA16(afr[mf], Breg[nf][s5], acc[mf][nf], 0, 0, 0);
        }
        __builtin_amdgcn_s_barrier();
        __builtin_amdgcn_sched_barrier(0);

        int p0 = tt * 32;
#pragma unroll
        for (int nf = 0; nf < 2; nf++) {
            float bval = nf ? bias1 : bias0;
            int n = n0w + nf * 16 + l15;
#pragma unroll
            for (int mf = 0; mf < 2; mf++) {
                float4v vv = acc[mf][nf];
#pragma unroll
                for (int r = 0; r < 4; r++) {
                    int m = p0 + mf * 16 + g * 4 + r;
                    Out[(size_t)m * DM + n] = vv[r] + bval;
                }
            }
        }
    }
}

// ============ launch =========================================================
extern "C" void kernel_launch(void* const* d_in, const int* in_sizes, int n_in,
                              void* d_out, int out_size, void* d_ws, size_t ws_size,
                              hipStream_t stream) {
    const float* q  = (const float*)d_in[0];
    const float* k  = (const float*)d_in[1];
    const float* v  = (const float*)d_in[2];
    const float* Wq = (const float*)d_in[3];
    const float* bq = (const float*)d_in[4];
    const float* Wk = (const float*)d_in[5];
    const float* bk = (const float*)d_in[6];
    const float* Wv = (const float*)d_in[7];
    const float* bv = (const float*)d_in[8];
    const float* Wo = (const float*)d_in[9];
    const float* bo = (const float*)d_in[10];

    const size_t WT_ELEMS  = (size_t)4 * DM * DM;
    const size_t QKV_ELEMS = (size_t)32 * KP * 64;
    const size_t ATT_ELEMS = (size_t)MROWS * DM;
    size_t need = (WT_ELEMS + 3 * QKV_ELEMS + ATT_ELEMS) * 2;
    if (ws_size < need) return;

    unsigned short* Wt = (unsigned short*)d_ws;
    unsigned short* Qb = Wt + WT_ELEMS;
    unsigned short* Kb = Qb + QKV_ELEMS;
    unsigned short* VT = Kb + QKV_ELEMS;
    unsigned short* Ab = VT + QKV_ELEMS;

    kprep<<<dim3(8, 8, 4), dim3(256), 0, stream>>>(Wq, Wk, Wv, Wo, Wt);
    kproj<<<dim3(1024), dim3(512), 0, stream>>>(q, k, v, Wt, bq, bk, bv,
                                                Qb, Kb, VT);
    kattn<<<dim3(NWIN, 32), dim3(384), 0, stream>>>(Qb, Kb, VT, Ab);
    kout<<<dim3(704), dim3(512), 0, stream>>>(Ab, Wt + 3 * DM * DM, bo,
                                              (float*)d_out);
}

// Round 15
// 216.252 us; speedup vs baseline: 1.2388x; 1.2388x over previous
//
#include <hip/hip_runtime.h>
#include <hip/hip_bf16.h>
#include <stdint.h>

// ---- problem constants ----
#define BATCH 4
#define SEQ   8400
#define DM    512
#define KP    8484      // SEQ + 2*42 (edge pad)
#define NWIN  100
#define STEP_ 84
#define PAD_  42
#define NKEY  126
#define MROWS 33600     // BATCH*SEQ
#define NTILES 266      // ceil(KP/32)
#define TPB   25        // tiles per work unit (11*25 = 275 >= 266)
#define NBI   11
#define OT_TPB 3        // kout tiles per work unit (350*3 = 1050 exact)
#define OT_NBI 350

typedef __attribute__((ext_vector_type(8))) short short8;
typedef __attribute__((ext_vector_type(4))) float float4v;
typedef __attribute__((ext_vector_type(4))) unsigned short ushort4v;

#define MFMA16 __builtin_amdgcn_mfma_f32_16x16x32_bf16

__device__ __forceinline__ unsigned short f2bf(float f) {
    union { float f; unsigned u; } v; v.f = f;
    return (unsigned short)((v.u + 0x7FFFu + ((v.u >> 16) & 1u)) >> 16);  // RNE
}
__device__ __forceinline__ unsigned short bfc(float f) {
    __hip_bfloat16 h = __float2bfloat16(f);
    union { __hip_bfloat16 h; unsigned short u; } v; v.h = h;
    return v.u;
}

typedef __attribute__((address_space(1))) const unsigned int as1_cu32;
typedef __attribute__((address_space(3))) unsigned int as3_u32;
__device__ __forceinline__ void gload16(const void* g, void* l) {
    __builtin_amdgcn_global_load_lds((as1_cu32*)g, (as3_u32*)l, 16, 0, 0);
}

// ============ prepass: W (f32 [k][n] 512x512) -> Wt (bf16 [n][k]) ============
__global__ __launch_bounds__(256) void kprep(const float* __restrict__ Wq,
                                             const float* __restrict__ Wk,
                                             const float* __restrict__ Wv,
                                             const float* __restrict__ Wo,
                                             unsigned short* __restrict__ Wt) {
    const float* src = blockIdx.z == 0 ? Wq : blockIdx.z == 1 ? Wk
                     : blockIdx.z == 2 ? Wv : Wo;
    unsigned short* dst = Wt + (size_t)blockIdx.z * DM * DM;
    __shared__ float t[64][65];
    int c = threadIdx.x & 63, r4 = threadIdx.x >> 6;
    int kb = blockIdx.x * 64, nb = blockIdx.y * 64;
    for (int i = 0; i < 16; i++) {
        int r = r4 * 16 + i;
        t[r][c] = src[(size_t)(kb + r) * DM + nb + c];
    }
    __syncthreads();
    for (int i = 0; i < 16; i++) {
        int r = r4 * 16 + i;
        dst[(size_t)(nb + r) * DM + kb + c] = f2bf(t[c][r]);
    }
}

// ============ kernel 1: weight-stationary fused pad+cvt+QKV projection =======
// R15: 272 blocks (fixes R14 coverage bug: 132 work units need ceil(132/8)*16
// = 272 L-slots), TPB=25 — halves per-grid B-reload count vs R9's 512/13.
// 8 waves; wave holds B[32 n][512 k] in regs. A tile [32 m][512 k] f32
// reg-prefetch -> cvt -> swizzled LDS (32 KB single buffer, 2 barriers/tile).
__global__ __launch_bounds__(512, 2) void kproj(const float* __restrict__ q,
                                                const float* __restrict__ k,
                                                const float* __restrict__ v,
                                                const unsigned short* __restrict__ Wt,
                                                const float* __restrict__ bq,
                                                const float* __restrict__ bk,
                                                const float* __restrict__ bv,
                                                unsigned short* __restrict__ Qb,
                                                unsigned short* __restrict__ Kb,
                                                unsigned short* __restrict__ VT) {
    int L = blockIdx.x;                          // 0..271
    int P = (L >> 4) * 8 + (L & 7);              // work unit
    int nhalf = (L >> 3) & 1;
    if (P >= 12 * NBI) return;
    int z = P / NBI, bi = P % NBI;
    int ten = z >> 2, b = z & 3;
    int t0 = bi * TPB;
    int tcnt = NTILES - t0; if (tcnt > TPB) tcnt = TPB;
    if (tcnt <= 0) return;

    const float* A = (ten == 0 ? q : ten == 1 ? k : v) + (size_t)b * SEQ * DM;
    const unsigned short* Wten = Wt + (size_t)ten * DM * DM;
    const float* bias = ten == 0 ? bq : ten == 1 ? bk : bv;
    float scale = ten == 0 ? 0.07715167498104595f : 1.f;   // 1/sqrt(168)

    __shared__ __align__(16) char lds[32768];    // [32 rows][1024 B] bf16 swz

    int tid = threadIdx.x, lane = tid & 63, w = tid >> 6;
    int l15 = lane & 15, g = lane >> 4;
    int n0w = nhalf * 256 + w * 32;              // wave's 32-col slice
    int h = n0w >> 6;
    int hb2 = h * BATCH + b;

    // ---- B slice into registers (once per block)
    short8 Breg[2][16];
#pragma unroll
    for (int nf = 0; nf < 2; nf++)
#pragma unroll
        for (int s5 = 0; s5 < 16; s5++)
            Breg[nf][s5] = *(const short8*)(Wten +
                (size_t)(n0w + nf * 16 + l15) * DM + s5 * 32 + g * 8);

    float bias0 = bias[n0w + l15];
    float bias1 = bias[n0w + 16 + l15];

    int srow = tid >> 4, sc = tid & 15;
    int woff = srow * 1024 + ((sc ^ (srow & 7)) << 4);

    auto loadreg = [&](float4v (&d)[8], int tt) {
        int p = tt * 32 + srow; if (p > KP - 1) p = KP - 1;
        int ar = p - PAD_; ar = ar < 0 ? 0 : (ar > SEQ - 1 ? SEQ - 1 : ar);
        const float* s = A + (size_t)ar * DM + sc * 8;
#pragma unroll
        for (int j = 0; j < 4; j++) {
            d[2 * j]     = *(const float4v*)(s + j * 128);
            d[2 * j + 1] = *(const float4v*)(s + j * 128 + 4);
        }
    };

    float4v a[8];
    loadreg(a, t0);

    for (int ti = 0; ti < tcnt; ti++) {
        int tt = t0 + ti;
#pragma unroll
        for (int j = 0; j < 4; j++) {
            float4v f0 = a[2 * j], f1 = a[2 * j + 1];
            short8 h0;
            h0[0] = (short)bfc(f0.x); h0[1] = (short)bfc(f0.y);
            h0[2] = (short)bfc(f0.z); h0[3] = (short)bfc(f0.w);
            h0[4] = (short)bfc(f1.x); h0[5] = (short)bfc(f1.y);
            h0[6] = (short)bfc(f1.z); h0[7] = (short)bfc(f1.w);
            *(short8*)(lds + woff + j * 256) = h0;
        }
        if (ti + 1 < tcnt) loadreg(a, tt + 1);
        __builtin_amdgcn_sched_barrier(0);
        asm volatile("s_waitcnt lgkmcnt(0)" ::: "memory");
        __builtin_amdgcn_s_barrier();
        __builtin_amdgcn_sched_barrier(0);

        float4v acc[2][2];
#pragma unroll
        for (int mf = 0; mf < 2; mf++)
#pragma unroll
            for (int nf = 0; nf < 2; nf++) {
                float4v zz = {0.f, 0.f, 0.f, 0.f}; acc[mf][nf] = zz;
            }
#pragma unroll
        for (int s5 = 0; s5 < 16; s5++) {
            short8 afr[2];
#pragma unroll
            for (int mf = 0; mf < 2; mf++) {
                int row = mf * 16 + l15, c = s5 * 4 + g;
                afr[mf] = *(const short8*)(lds + row * 1024 + ((c ^ (row & 7)) << 4));
            }
#pragma unroll
            for (int mf = 0; mf < 2; mf++)
#pragma unroll
                for (int nf = 0; nf < 2; nf++)
                    acc[mf][nf] = MFMA16(afr[mf], Breg[nf][s5], acc[mf][nf], 0, 0, 0);
        }
        __builtin_amdgcn_s_barrier();            // reads done -> buf reusable
        __builtin_amdgcn_sched_barrier(0);

        int p0 = tt * 32;
        if (ten <= 1) {
            unsigned short* O = ten == 0 ? Qb : Kb;
#pragma unroll
            for (int nf = 0; nf < 2; nf++) {
                float bval = nf ? bias1 : bias0;
                int d = ((n0w + nf * 16) & 63) + l15;
                unsigned short* op = O + (size_t)hb2 * KP * 64 + d;
#pragma unroll
                for (int mf = 0; mf < 2; mf++) {
                    float4v vv = acc[mf][nf];
#pragma unroll
                    for (int r = 0; r < 4; r++) {
                        int p = p0 + mf * 16 + g * 4 + r;
                        if (p < KP)
                            op[(size_t)p * 64] = f2bf((vv[r] + bval) * scale);
                    }
                }
            }
        } else {
#pragma unroll
            for (int nf = 0; nf < 2; nf++) {
                float bval = nf ? bias1 : bias0;
                int d = ((n0w + nf * 16) & 63) + l15;
                unsigned short* base = VT + ((size_t)hb2 * 64 + d) * KP;
#pragma unroll
                for (int mf = 0; mf < 2; mf++) {
                    int p = p0 + mf * 16 + g * 4;
                    if (p <= KP - 4) {
                        float4v vv = acc[mf][nf];
                        ushort4v wv;
                        wv[0] = f2bf(vv.x + bval); wv[1] = f2bf(vv.y + bval);
                        wv[2] = f2bf(vv.z + bval); wv[3] = f2bf(vv.w + bval);
                        *(ushort4v*)(base + p) = wv;
                    }
                }
            }
        }
    }
}

// ============ kernel 2: windowed causal attention (44 KB LDS, R11 version) ===
__global__ __launch_bounds__(384) void kattn(const unsigned short* __restrict__ Qb,
                                             const unsigned short* __restrict__ Kb,
                                             const unsigned short* __restrict__ VT,
                                             unsigned short* __restrict__ attn) {
    int win = blockIdx.x, hb = blockIdx.y;
    int h = hb >> 2, b = hb & 3;
    const unsigned short* Qg = Qb + (size_t)hb * KP * 64;
    const unsigned short* Kg = Kb + (size_t)hb * KP * 64;
    const unsigned short* Vt = VT + (size_t)hb * 64 * KP;
    int p0 = win * STEP_;

    __shared__ __align__(16) char lds[45056];

    int tid = threadIdx.x, lane = tid & 63, f = tid >> 6;
    int l15 = lane & 15, g = lane >> 4;

#pragma unroll
    for (int it = 0; it < 5; it++) {
        int base = it * 384 + f * 64;
        if (base < 768) {                       // Q chunks
            int c = base + lane;
            int qi = c >> 3, kg = (c & 7) ^ (qi & 7);
            gload16(Qg + (size_t)(p0 + PAD_ + qi) * 64 + kg * 8, lds + base * 16);
        } else if (base < 1792) {               // K chunks
            int c = base + lane - 768;
            int x = c >> 3, kg = (c & 7) ^ (x & 7);
            gload16(Kg + (size_t)(p0 + x) * 64 + kg * 8, lds + base * 16);
        }
    }
    for (int c = tid; c < 2048; c += 384) {
        int d = c >> 5, c2 = c & 31;
        ushort4v wv = *(const ushort4v*)(Vt + (size_t)d * KP + p0 + c2 * 4);
        int cx = c2 >> 1;
        *(ushort4v*)(lds + 28672 + d * 256 + (((cx ^ (d & 7)) << 4) | ((c2 & 1) * 8))) = wv;
    }
    __syncthreads();

    short8 bq2[2];
    {
        int r = f * 16 + l15;
#pragma unroll
        for (int ks = 0; ks < 2; ks++) {
            int kg = ks * 4 + g;
            bq2[ks] = *(const short8*)(lds + r * 128 + ((kg ^ (r & 7)) << 4));
        }
    }
    float4v st[8];
#pragma unroll
    for (int xf = 0; xf < 8; xf++) {
        float4v zz = {0.f,0.f,0.f,0.f}; st[xf] = zz;
#pragma unroll
        for (int ks = 0; ks < 2; ks++) {
            int r = xf * 16 + l15;
            int kg = ks * 4 + g;
            short8 a = *(const short8*)(lds + 12288 + r * 128 + ((kg ^ (r & 7)) << 4));
            st[xf] = MFMA16(a, bq2[ks], st[xf], 0, 0, 0);
        }
    }

    int w_abs = PAD_ + f * 16 + l15;
    int w_eff = w_abs > 125 ? 125 : w_abs;
    float mx = -1e30f;
#pragma unroll
    for (int xf = 0; xf < 8; xf++)
#pragma unroll
        for (int r = 0; r < 4; r++) {
            int x = xf * 16 + g * 4 + r;
            float vv = st[xf][r];
            if (x > w_eff) vv = -1e30f;
            st[xf][r] = vv;
            mx = fmaxf(mx, vv);
        }
    mx = fmaxf(mx, __shfl_xor(mx, 16));
    mx = fmaxf(mx, __shfl_xor(mx, 32));
    float s = 0.f;
#pragma unroll
    for (int xf = 0; xf < 8; xf++)
#pragma unroll
        for (int r = 0; r < 4; r++) {
            float e = __expf(st[xf][r] - mx);
            st[xf][r] = e;
            s += e;
        }
    s += __shfl_xor(s, 16);
    s += __shfl_xor(s, 32);
    float inv = 1.f / s;

    __syncthreads();   // Ql/Kl reads done -> Pl may clobber [0,24576)

    {
        int qi = f * 16 + l15;
#pragma unroll
        for (int xf = 0; xf < 8; xf++) {
            ushort4v pw;
#pragma unroll
            for (int r = 0; r < 4; r++) pw[r] = f2bf(st[xf][r] * inv);
            int xc = 2 * xf + (g >> 1);
            *(ushort4v*)(lds + qi * 256 + ((xc ^ (qi & 7)) << 4) + (g & 1) * 8) = pw;
        }
    }
    asm volatile("s_waitcnt lgkmcnt(0)" ::: "memory");
    __builtin_amdgcn_sched_barrier(0);

    float4v pv[4];
#pragma unroll
    for (int j = 0; j < 4; j++) { float4v zz = {0.f,0.f,0.f,0.f}; pv[j] = zz; }
    int qi = f * 16 + l15;
#pragma unroll
    for (int g2 = 0; g2 < 4; g2++) {
        int xc = g2 * 4 + g;
        short8 a = *(const short8*)(lds + qi * 256 + ((xc ^ (qi & 7)) << 4));
#pragma unroll
        for (int j = 0; j < 4; j++) {
            int d = j * 16 + l15;
            short8 bvv = *(const short8*)(lds + 28672 + d * 256 + ((xc ^ (d & 7)) << 4));
            pv[j] = MFMA16(a, bvv, pv[j], 0, 0, 0);
        }
    }

    __syncthreads();   // PV reads of P done -> Ol may clobber [0,12288)

    unsigned short* Ol = (unsigned short*)lds;
#pragma unroll
    for (int j = 0; j < 4; j++) {
        int d = j * 16 + l15;
#pragma unroll
        for (int r = 0; r < 4; r++) {
            int qq = f * 16 + g * 4 + r;
            int byte = qq * 128 + ((((d >> 3) ^ (qq & 7))) << 4) + (d & 7) * 2;
            *(unsigned short*)((char*)Ol + byte) = f2bf(pv[j][r]);
        }
    }
    __syncthreads();
    for (int c = tid; c < 672; c += 384) {
        int qq = c >> 3, ch = c & 7;
        short8 hv = *(const short8*)((char*)Ol + qq * 128 + ((ch ^ (qq & 7)) << 4));
        size_t off = ((size_t)(b * SEQ + win * STEP_ + qq) * DM) + h * 64 + ch * 8;
        *(short8*)(attn + off) = hv;
    }
}

// ============ kernel 3: weight-stationary output projection ==================
__global__ __launch_bounds__(512, 2) void kout(const unsigned short* __restrict__ Ab,
                                               const unsigned short* __restrict__ W,
                                               const float* __restrict__ bias,
                                               float* __restrict__ Out) {
    int L = blockIdx.x;                          // 0..703
    int P = (L >> 4) * 8 + (L & 7);
    int nhalf = (L >> 3) & 1;
    if (P >= OT_NBI) return;
    int t0 = P * OT_TPB;

    __shared__ __align__(16) char lds[32768];

    int tid = threadIdx.x, lane = tid & 63, w = tid >> 6;
    int l15 = lane & 15, g = lane >> 4;
    int n0w = nhalf * 256 + w * 32;

    short8 Breg[2][16];
#pragma unroll
    for (int nf = 0; nf < 2; nf++)
#pragma unroll
        for (int s5 = 0; s5 < 16; s5++)
            Breg[nf][s5] = *(const short8*)(W +
                (size_t)(n0w + nf * 16 + l15) * DM + s5 * 32 + g * 8);

    float bias0 = bias[n0w + l15];
    float bias1 = bias[n0w + 16 + l15];

    int srow = tid >> 4, sc = tid & 15;

    auto loadreg = [&](short8 (&d)[4], int tt) {
        const unsigned short* s = Ab + (size_t)(tt * 32 + srow) * DM;
#pragma unroll
        for (int j = 0; j < 4; j++)
            d[j] = *(const short8*)(s + (sc + j * 16) * 8);
    };

    short8 a[4];
    loadreg(a, t0);

    for (int ti = 0; ti < OT_TPB; ti++) {
        int tt = t0 + ti;
#pragma unroll
        for (int j = 0; j < 4; j++)
            *(short8*)(lds + srow * 1024 +
                       (((sc + j * 16) ^ (srow & 7)) << 4)) = a[j];
        if (ti + 1 < OT_TPB) loadreg(a, tt + 1);
        __builtin_amdgcn_sched_barrier(0);
        asm volatile("s_waitcnt lgkmcnt(0)" ::: "memory");
        __builtin_amdgcn_s_barrier();
        __builtin_amdgcn_sched_barrier(0);

        float4v acc[2][2];
#pragma unroll
        for (int mf = 0; mf < 2; mf++)
#pragma unroll
            for (int nf = 0; nf < 2; nf++) {
                float4v zz = {0.f, 0.f, 0.f, 0.f}; acc[mf][nf] = zz;
            }
#pragma unroll
        for (int s5 = 0; s5 < 16; s5++) {
            short8 afr[2];
#pragma unroll
            for (int mf = 0; mf < 2; mf++) {
                int row = mf * 16 + l15, c = s5 * 4 + g;
                afr[mf] = *(const short8*)(lds + row * 1024 + ((c ^ (row & 7)) << 4));
            }
#pragma unroll
            for (int mf = 0; mf < 2; mf++)
#pragma unroll
                for (int nf = 0; nf < 2; nf++)
                    acc[mf][nf] = MFMA16(afr[mf], Breg[nf][s5], acc[mf][nf], 0, 0, 0);
        }
        __builtin_amdgcn_s_barrier();
        __builtin_amdgcn_sched_barrier(0);

        int p0 = tt * 32;
#pragma unroll
        for (int nf = 0; nf < 2; nf++) {
            float bval = nf ? bias1 : bias0;
            int n = n0w + nf * 16 + l15;
#pragma unroll
            for (int mf = 0; mf < 2; mf++) {
                float4v vv = acc[mf][nf];
#pragma unroll
                for (int r = 0; r < 4; r++) {
                    int m = p0 + mf * 16 + g * 4 + r;
                    Out[(size_t)m * DM + n] = vv[r] + bval;
                }
            }
        }
    }
}

// ============ launch =========================================================
extern "C" void kernel_launch(void* const* d_in, const int* in_sizes, int n_in,
                              void* d_out, int out_size, void* d_ws, size_t ws_size,
                              hipStream_t stream) {
    const float* q  = (const float*)d_in[0];
    const float* k  = (const float*)d_in[1];
    const float* v  = (const float*)d_in[2];
    const float* Wq = (const float*)d_in[3];
    const float* bq = (const float*)d_in[4];
    const float* Wk = (const float*)d_in[5];
    const float* bk = (const float*)d_in[6];
    const float* Wv = (const float*)d_in[7];
    const float* bv = (const float*)d_in[8];
    const float* Wo = (const float*)d_in[9];
    const float* bo = (const float*)d_in[10];

    const size_t WT_ELEMS  = (size_t)4 * DM * DM;
    const size_t QKV_ELEMS = (size_t)32 * KP * 64;
    const size_t ATT_ELEMS = (size_t)MROWS * DM;
    size_t need = (WT_ELEMS + 3 * QKV_ELEMS + ATT_ELEMS) * 2;
    if (ws_size < need) return;

    unsigned short* Wt = (unsigned short*)d_ws;
    unsigned short* Qb = Wt + WT_ELEMS;
    unsigned short* Kb = Qb + QKV_ELEMS;
    unsigned short* VT = Kb + QKV_ELEMS;
    unsigned short* Ab = VT + QKV_ELEMS;

    kprep<<<dim3(8, 8, 4), dim3(256), 0, stream>>>(Wq, Wk, Wv, Wo, Wt);
    kproj<<<dim3(272), dim3(512), 0, stream>>>(q, k, v, Wt, bq, bk, bv,
                                               Qb, Kb, VT);
    kattn<<<dim3(NWIN, 32), dim3(384), 0, stream>>>(Qb, Kb, VT, Ab);
    kout<<<dim3(704), dim3(512), 0, stream>>>(Ab, Wt + 3 * DM * DM, bo,
                                              (float*)d_out);
}

// Round 16
// 189.180 us; speedup vs baseline: 1.4161x; 1.1431x over previous
//
#include <hip/hip_runtime.h>
#include <hip/hip_bf16.h>
#include <stdint.h>

// ---- problem constants ----
#define BATCH 4
#define SEQ   8400
#define DM    512
#define KP    8484      // SEQ + 2*42 (edge pad)
#define NWIN  100
#define STEP_ 84
#define PAD_  42
#define NKEY  126
#define MROWS 33600     // BATCH*SEQ
#define NTILES 266      // ceil(KP/32)
#define TPB   13        // tiles per work unit (21*13 >= 266)  [R9/R11 config]
#define NBI   21
#define OT_TPB 3        // kout tiles per work unit (350*3 = 1050 exact)
#define OT_NBI 350

typedef __attribute__((ext_vector_type(8))) short short8;
typedef __attribute__((ext_vector_type(4))) float float4v;
typedef __attribute__((ext_vector_type(4))) unsigned short ushort4v;

#define MFMA16 __builtin_amdgcn_mfma_f32_16x16x32_bf16

__device__ __forceinline__ unsigned short f2bf(float f) {
    union { float f; unsigned u; } v; v.f = f;
    return (unsigned short)((v.u + 0x7FFFu + ((v.u >> 16) & 1u)) >> 16);  // RNE
}
__device__ __forceinline__ unsigned short bfc(float f) {
    __hip_bfloat16 h = __float2bfloat16(f);
    union { __hip_bfloat16 h; unsigned short u; } v; v.h = h;
    return v.u;
}

typedef __attribute__((address_space(1))) const unsigned int as1_cu32;
typedef __attribute__((address_space(3))) unsigned int as3_u32;
__device__ __forceinline__ void gload16(const void* g, void* l) {
    __builtin_amdgcn_global_load_lds((as1_cu32*)g, (as3_u32*)l, 16, 0, 0);
}

// ============ prepass: W (f32 [k][n] 512x512) -> Wt (bf16 [n][k]) ============
__global__ __launch_bounds__(256) void kprep(const float* __restrict__ Wq,
                                             const float* __restrict__ Wk,
                                             const float* __restrict__ Wv,
                                             const float* __restrict__ Wo,
                                             unsigned short* __restrict__ Wt) {
    const float* src = blockIdx.z == 0 ? Wq : blockIdx.z == 1 ? Wk
                     : blockIdx.z == 2 ? Wv : Wo;
    unsigned short* dst = Wt + (size_t)blockIdx.z * DM * DM;
    __shared__ float t[64][65];
    int c = threadIdx.x & 63, r4 = threadIdx.x >> 6;
    int kb = blockIdx.x * 64, nb = blockIdx.y * 64;
    for (int i = 0; i < 16; i++) {
        int r = r4 * 16 + i;
        t[r][c] = src[(size_t)(kb + r) * DM + nb + c];
    }
    __syncthreads();
    for (int i = 0; i < 16; i++) {
        int r = r4 * 16 + i;
        dst[(size_t)(nb + r) * DM + kb + c] = f2bf(t[c][r]);
    }
}

// ============ kernel 1: weight-stationary fused pad+cvt+QKV projection =======
// R11-best config: 512 blocks, TPB=13, 8 waves; wave holds B[32 n][512 k] in
// 128 regs. A tile [32 m][512 k]: f32 reg-prefetch -> cvt -> swizzled LDS
// (32 KB single buffer, 2 barriers/tile). + T5 setprio around MFMA cluster.
__global__ __launch_bounds__(512, 2) void kproj(const float* __restrict__ q,
                                                const float* __restrict__ k,
                                                const float* __restrict__ v,
                                                const unsigned short* __restrict__ Wt,
                                                const float* __restrict__ bq,
                                                const float* __restrict__ bk,
                                                const float* __restrict__ bv,
                                                unsigned short* __restrict__ Qb,
                                                unsigned short* __restrict__ Kb,
                                                unsigned short* __restrict__ VT) {
    int L = blockIdx.x;                          // 0..511
    int P = (L >> 4) * 8 + (L & 7);              // work unit
    int nhalf = (L >> 3) & 1;
    if (P >= 12 * NBI) return;
    int z = P / NBI, bi = P % NBI;
    int ten = z >> 2, b = z & 3;
    int t0 = bi * TPB;
    int tcnt = NTILES - t0; if (tcnt > TPB) tcnt = TPB;
    if (tcnt <= 0) return;

    const float* A = (ten == 0 ? q : ten == 1 ? k : v) + (size_t)b * SEQ * DM;
    const unsigned short* Wten = Wt + (size_t)ten * DM * DM;
    const float* bias = ten == 0 ? bq : ten == 1 ? bk : bv;
    float scale = ten == 0 ? 0.07715167498104595f : 1.f;   // 1/sqrt(168)

    __shared__ __align__(16) char lds[32768];    // [32 rows][1024 B] bf16 swz

    int tid = threadIdx.x, lane = tid & 63, w = tid >> 6;
    int l15 = lane & 15, g = lane >> 4;
    int n0w = nhalf * 256 + w * 32;              // wave's 32-col slice
    int h = n0w >> 6;
    int hb2 = h * BATCH + b;

    // ---- B slice into registers (once per block)
    short8 Breg[2][16];
#pragma unroll
    for (int nf = 0; nf < 2; nf++)
#pragma unroll
        for (int s5 = 0; s5 < 16; s5++)
            Breg[nf][s5] = *(const short8*)(Wten +
                (size_t)(n0w + nf * 16 + l15) * DM + s5 * 32 + g * 8);

    float bias0 = bias[n0w + l15];
    float bias1 = bias[n0w + 16 + l15];

    int srow = tid >> 4, sc = tid & 15;
    int woff = srow * 1024 + ((sc ^ (srow & 7)) << 4);

    auto loadreg = [&](float4v (&d)[8], int tt) {
        int p = tt * 32 + srow; if (p > KP - 1) p = KP - 1;
        int ar = p - PAD_; ar = ar < 0 ? 0 : (ar > SEQ - 1 ? SEQ - 1 : ar);
        const float* s = A + (size_t)ar * DM + sc * 8;
#pragma unroll
        for (int j = 0; j < 4; j++) {
            d[2 * j]     = *(const float4v*)(s + j * 128);
            d[2 * j + 1] = *(const float4v*)(s + j * 128 + 4);
        }
    };

    float4v a[8];
    loadreg(a, t0);

    for (int ti = 0; ti < tcnt; ti++) {
        int tt = t0 + ti;
#pragma unroll
        for (int j = 0; j < 4; j++) {
            float4v f0 = a[2 * j], f1 = a[2 * j + 1];
            short8 h0;
            h0[0] = (short)bfc(f0.x); h0[1] = (short)bfc(f0.y);
            h0[2] = (short)bfc(f0.z); h0[3] = (short)bfc(f0.w);
            h0[4] = (short)bfc(f1.x); h0[5] = (short)bfc(f1.y);
            h0[6] = (short)bfc(f1.z); h0[7] = (short)bfc(f1.w);
            *(short8*)(lds + woff + j * 256) = h0;
        }
        if (ti + 1 < tcnt) loadreg(a, tt + 1);
        __builtin_amdgcn_sched_barrier(0);
        asm volatile("s_waitcnt lgkmcnt(0)" ::: "memory");
        __builtin_amdgcn_s_barrier();
        __builtin_amdgcn_sched_barrier(0);

        float4v acc[2][2];
#pragma unroll
        for (int mf = 0; mf < 2; mf++)
#pragma unroll
            for (int nf = 0; nf < 2; nf++) {
                float4v zz = {0.f, 0.f, 0.f, 0.f}; acc[mf][nf] = zz;
            }
        __builtin_amdgcn_s_setprio(1);           // T5: favor MFMA-issuing wave
#pragma unroll
        for (int s5 = 0; s5 < 16; s5++) {
            short8 afr[2];
#pragma unroll
            for (int mf = 0; mf < 2; mf++) {
                int row = mf * 16 + l15, c = s5 * 4 + g;
                afr[mf] = *(const short8*)(lds + row * 1024 + ((c ^ (row & 7)) << 4));
            }
#pragma unroll
            for (int mf = 0; mf < 2; mf++)
#pragma unroll
                for (int nf = 0; nf < 2; nf++)
                    acc[mf][nf] = MFMA16(afr[mf], Breg[nf][s5], acc[mf][nf], 0, 0, 0);
        }
        __builtin_amdgcn_s_setprio(0);
        __builtin_amdgcn_s_barrier();            // reads done -> buf reusable
        __builtin_amdgcn_sched_barrier(0);

        int p0 = tt * 32;
        if (ten <= 1) {
            unsigned short* O = ten == 0 ? Qb : Kb;
#pragma unroll
            for (int nf = 0; nf < 2; nf++) {
                float bval = nf ? bias1 : bias0;
                int d = ((n0w + nf * 16) & 63) + l15;
                unsigned short* op = O + (size_t)hb2 * KP * 64 + d;
#pragma unroll
                for (int mf = 0; mf < 2; mf++) {
                    float4v vv = acc[mf][nf];
#pragma unroll
                    for (int r = 0; r < 4; r++) {
                        int p = p0 + mf * 16 + g * 4 + r;
                        if (p < KP)
                            op[(size_t)p * 64] = f2bf((vv[r] + bval) * scale);
                    }
                }
            }
        } else {
#pragma unroll
            for (int nf = 0; nf < 2; nf++) {
                float bval = nf ? bias1 : bias0;
                int d = ((n0w + nf * 16) & 63) + l15;
                unsigned short* base = VT + ((size_t)hb2 * 64 + d) * KP;
#pragma unroll
                for (int mf = 0; mf < 2; mf++) {
                    int p = p0 + mf * 16 + g * 4;
                    if (p <= KP - 4) {
                        float4v vv = acc[mf][nf];
                        ushort4v wv;
                        wv[0] = f2bf(vv.x + bval); wv[1] = f2bf(vv.y + bval);
                        wv[2] = f2bf(vv.z + bval); wv[3] = f2bf(vv.w + bval);
                        *(ushort4v*)(base + p) = wv;
                    }
                }
            }
        }
    }
}

// ============ kernel 2: windowed causal attention (44 KB LDS, R11 version) ===
__global__ __launch_bounds__(384) void kattn(const unsigned short* __restrict__ Qb,
                                             const unsigned short* __restrict__ Kb,
                                             const unsigned short* __restrict__ VT,
                                             unsigned short* __restrict__ attn) {
    int win = blockIdx.x, hb = blockIdx.y;
    int h = hb >> 2, b = hb & 3;
    const unsigned short* Qg = Qb + (size_t)hb * KP * 64;
    const unsigned short* Kg = Kb + (size_t)hb * KP * 64;
    const unsigned short* Vt = VT + (size_t)hb * 64 * KP;
    int p0 = win * STEP_;

    __shared__ __align__(16) char lds[45056];

    int tid = threadIdx.x, lane = tid & 63, f = tid >> 6;
    int l15 = lane & 15, g = lane >> 4;

#pragma unroll
    for (int it = 0; it < 5; it++) {
        int base = it * 384 + f * 64;
        if (base < 768) {                       // Q chunks
            int c = base + lane;
            int qi = c >> 3, kg = (c & 7) ^ (qi & 7);
            gload16(Qg + (size_t)(p0 + PAD_ + qi) * 64 + kg * 8, lds + base * 16);
        } else if (base < 1792) {               // K chunks
            int c = base + lane - 768;
            int x = c >> 3, kg = (c & 7) ^ (x & 7);
            gload16(Kg + (size_t)(p0 + x) * 64 + kg * 8, lds + base * 16);
        }
    }
    for (int c = tid; c < 2048; c += 384) {
        int d = c >> 5, c2 = c & 31;
        ushort4v wv = *(const ushort4v*)(Vt + (size_t)d * KP + p0 + c2 * 4);
        int cx = c2 >> 1;
        *(ushort4v*)(lds + 28672 + d * 256 + (((cx ^ (d & 7)) << 4) | ((c2 & 1) * 8))) = wv;
    }
    __syncthreads();

    short8 bq2[2];
    {
        int r = f * 16 + l15;
#pragma unroll
        for (int ks = 0; ks < 2; ks++) {
            int kg = ks * 4 + g;
            bq2[ks] = *(const short8*)(lds + r * 128 + ((kg ^ (r & 7)) << 4));
        }
    }
    float4v st[8];
#pragma unroll
    for (int xf = 0; xf < 8; xf++) {
        float4v zz = {0.f,0.f,0.f,0.f}; st[xf] = zz;
#pragma unroll
        for (int ks = 0; ks < 2; ks++) {
            int r = xf * 16 + l15;
            int kg = ks * 4 + g;
            short8 a = *(const short8*)(lds + 12288 + r * 128 + ((kg ^ (r & 7)) << 4));
            st[xf] = MFMA16(a, bq2[ks], st[xf], 0, 0, 0);
        }
    }

    int w_abs = PAD_ + f * 16 + l15;
    int w_eff = w_abs > 125 ? 125 : w_abs;
    float mx = -1e30f;
#pragma unroll
    for (int xf = 0; xf < 8; xf++)
#pragma unroll
        for (int r = 0; r < 4; r++) {
            int x = xf * 16 + g * 4 + r;
            float vv = st[xf][r];
            if (x > w_eff) vv = -1e30f;
            st[xf][r] = vv;
            mx = fmaxf(mx, vv);
        }
    mx = fmaxf(mx, __shfl_xor(mx, 16));
    mx = fmaxf(mx, __shfl_xor(mx, 32));
    float s = 0.f;
#pragma unroll
    for (int xf = 0; xf < 8; xf++)
#pragma unroll
        for (int r = 0; r < 4; r++) {
            float e = __expf(st[xf][r] - mx);
            st[xf][r] = e;
            s += e;
        }
    s += __shfl_xor(s, 16);
    s += __shfl_xor(s, 32);
    float inv = 1.f / s;

    __syncthreads();   // Ql/Kl reads done -> Pl may clobber [0,24576)

    {
        int qi = f * 16 + l15;
#pragma unroll
        for (int xf = 0; xf < 8; xf++) {
            ushort4v pw;
#pragma unroll
            for (int r = 0; r < 4; r++) pw[r] = f2bf(st[xf][r] * inv);
            int xc = 2 * xf + (g >> 1);
            *(ushort4v*)(lds + qi * 256 + ((xc ^ (qi & 7)) << 4) + (g & 1) * 8) = pw;
        }
    }
    asm volatile("s_waitcnt lgkmcnt(0)" ::: "memory");
    __builtin_amdgcn_sched_barrier(0);

    float4v pv[4];
#pragma unroll
    for (int j = 0; j < 4; j++) { float4v zz = {0.f,0.f,0.f,0.f}; pv[j] = zz; }
    int qi = f * 16 + l15;
#pragma unroll
    for (int g2 = 0; g2 < 4; g2++) {
        int xc = g2 * 4 + g;
        short8 a = *(const short8*)(lds + qi * 256 + ((xc ^ (qi & 7)) << 4));
#pragma unroll
        for (int j = 0; j < 4; j++) {
            int d = j * 16 + l15;
            short8 bvv = *(const short8*)(lds + 28672 + d * 256 + ((xc ^ (d & 7)) << 4));
            pv[j] = MFMA16(a, bvv, pv[j], 0, 0, 0);
        }
    }

    __syncthreads();   // PV reads of P done -> Ol may clobber [0,12288)

    unsigned short* Ol = (unsigned short*)lds;
#pragma unroll
    for (int j = 0; j < 4; j++) {
        int d = j * 16 + l15;
#pragma unroll
        for (int r = 0; r < 4; r++) {
            int qq = f * 16 + g * 4 + r;
            int byte = qq * 128 + ((((d >> 3) ^ (qq & 7))) << 4) + (d & 7) * 2;
            *(unsigned short*)((char*)Ol + byte) = f2bf(pv[j][r]);
        }
    }
    __syncthreads();
    for (int c = tid; c < 672; c += 384) {
        int qq = c >> 3, ch = c & 7;
        short8 hv = *(const short8*)((char*)Ol + qq * 128 + ((ch ^ (qq & 7)) << 4));
        size_t off = ((size_t)(b * SEQ + win * STEP_ + qq) * DM) + h * 64 + ch * 8;
        *(short8*)(attn + off) = hv;
    }
}

// ============ kernel 3: weight-stationary output projection ==================
__global__ __launch_bounds__(512, 2) void kout(const unsigned short* __restrict__ Ab,
                                               const unsigned short* __restrict__ W,
                                               const float* __restrict__ bias,
                                               float* __restrict__ Out) {
    int L = blockIdx.x;                          // 0..703
    int P = (L >> 4) * 8 + (L & 7);
    int nhalf = (L >> 3) & 1;
    if (P >= OT_NBI) return;
    int t0 = P * OT_TPB;

    __shared__ __align__(16) char lds[32768];

    int tid = threadIdx.x, lane = tid & 63, w = tid >> 6;
    int l15 = lane & 15, g = lane >> 4;
    int n0w = nhalf * 256 + w * 32;

    short8 Breg[2][16];
#pragma unroll
    for (int nf = 0; nf < 2; nf++)
#pragma unroll
        for (int s5 = 0; s5 < 16; s5++)
            Breg[nf][s5] = *(const short8*)(W +
                (size_t)(n0w + nf * 16 + l15) * DM + s5 * 32 + g * 8);

    float bias0 = bias[n0w + l15];
    float bias1 = bias[n0w + 16 + l15];

    int srow = tid >> 4, sc = tid & 15;

    auto loadreg = [&](short8 (&d)[4], int tt) {
        const unsigned short* s = Ab + (size_t)(tt * 32 + srow) * DM;
#pragma unroll
        for (int j = 0; j < 4; j++)
            d[j] = *(const short8*)(s + (sc + j * 16) * 8);
    };

    short8 a[4];
    loadreg(a, t0);

    for (int ti = 0; ti < OT_TPB; ti++) {
        int tt = t0 + ti;
#pragma unroll
        for (int j = 0; j < 4; j++)
            *(short8*)(lds + srow * 1024 +
                       (((sc + j * 16) ^ (srow & 7)) << 4)) = a[j];
        if (ti + 1 < OT_TPB) loadreg(a, tt + 1);
        __builtin_amdgcn_sched_barrier(0);
        asm volatile("s_waitcnt lgkmcnt(0)" ::: "memory");
        __builtin_amdgcn_s_barrier();
        __builtin_amdgcn_sched_barrier(0);

        float4v acc[2][2];
#pragma unroll
        for (int mf = 0; mf < 2; mf++)
#pragma unroll
            for (int nf = 0; nf < 2; nf++) {
                float4v zz = {0.f, 0.f, 0.f, 0.f}; acc[mf][nf] = zz;
            }
        __builtin_amdgcn_s_setprio(1);           // T5
#pragma unroll
        for (int s5 = 0; s5 < 16; s5++) {
            short8 afr[2];
#pragma unroll
            for (int mf = 0; mf < 2; mf++) {
                int row = mf * 16 + l15, c = s5 * 4 + g;
                afr[mf] = *(const short8*)(lds + row * 1024 + ((c ^ (row & 7)) << 4));
            }
#pragma unroll
            for (int mf = 0; mf < 2; mf++)
#pragma unroll
                for (int nf = 0; nf < 2; nf++)
                    acc[mf][nf] = MFMA16(afr[mf], Breg[nf][s5], acc[mf][nf], 0, 0, 0);
        }
        __builtin_amdgcn_s_setprio(0);
        __builtin_amdgcn_s_barrier();
        __builtin_amdgcn_sched_barrier(0);

        int p0 = tt * 32;
#pragma unroll
        for (int nf = 0; nf < 2; nf++) {
            float bval = nf ? bias1 : bias0;
            int n = n0w + nf * 16 + l15;
#pragma unroll
            for (int mf = 0; mf < 2; mf++) {
                float4v vv = acc[mf][nf];
#pragma unroll
                for (int r = 0; r < 4; r++) {
                    int m = p0 + mf * 16 + g * 4 + r;
                    Out[(size_t)m * DM + n] = vv[r] + bval;
                }
            }
        }
    }
}

// ============ launch =========================================================
extern "C" void kernel_launch(void* const* d_in, const int* in_sizes, int n_in,
                              void* d_out, int out_size, void* d_ws, size_t ws_size,
                              hipStream_t stream) {
    const float* q  = (const float*)d_in[0];
    const float* k  = (const float*)d_in[1];
    const float* v  = (const float*)d_in[2];
    const float* Wq = (const float*)d_in[3];
    const float* bq = (const float*)d_in[4];
    const float* Wk = (const float*)d_in[5];
    const float* bk = (const float*)d_in[6];
    const float* Wv = (const float*)d_in[7];
    const float* bv = (const float*)d_in[8];
    const float* Wo = (const float*)d_in[9];
    const float* bo = (const float*)d_in[10];

    const size_t WT_ELEMS  = (size_t)4 * DM * DM;
    const size_t QKV_ELEMS = (size_t)32 * KP * 64;
    const size_t ATT_ELEMS = (size_t)MROWS * DM;
    size_t need = (WT_ELEMS + 3 * QKV_ELEMS + ATT_ELEMS) * 2;
    if (ws_size < need) return;

    unsigned short* Wt = (unsigned short*)d_ws;
    unsigned short* Qb = Wt + WT_ELEMS;
    unsigned short* Kb = Qb + QKV_ELEMS;
    unsigned short* VT = Kb + QKV_ELEMS;
    unsigned short* Ab = VT + QKV_ELEMS;

    kprep<<<dim3(8, 8, 4), dim3(256), 0, stream>>>(Wq, Wk, Wv, Wo, Wt);
    kproj<<<dim3(512), dim3(512), 0, stream>>>(q, k, v, Wt, bq, bk, bv,
                                               Qb, Kb, VT);
    kattn<<<dim3(NWIN, 32), dim3(384), 0, stream>>>(Qb, Kb, VT, Ab);
    kout<<<dim3(704), dim3(512), 0, stream>>>(Ab, Wt + 3 * DM * DM, bo,
                                              (float*)d_out);
}

// Round 17
// 186.980 us; speedup vs baseline: 1.4328x; 1.0118x over previous
//
#include <hip/hip_runtime.h>
#include <hip/hip_bf16.h>
#include <stdint.h>

// ---- problem constants ----
#define BATCH 4
#define SEQ   8400
#define DM    512
#define KP    8484      // SEQ + 2*42 (edge pad)
#define NWIN  100
#define STEP_ 84
#define PAD_  42
#define NKEY  126
#define MROWS 33600     // BATCH*SEQ
#define NTILES 266      // ceil(KP/32)
#define TPB   13        // tiles per work unit (21*13 >= 266)  [best: R9/R11]
#define NBI   21
#define OT_TPB 3        // kout tiles per work unit (350*3 = 1050 exact)
#define OT_NBI 350

typedef __attribute__((ext_vector_type(8))) short short8;
typedef __attribute__((ext_vector_type(4))) float float4v;
typedef __attribute__((ext_vector_type(4))) unsigned short ushort4v;

#define MFMA16 __builtin_amdgcn_mfma_f32_16x16x32_bf16

__device__ __forceinline__ unsigned short f2bf(float f) {
    union { float f; unsigned u; } v; v.f = f;
    return (unsigned short)((v.u + 0x7FFFu + ((v.u >> 16) & 1u)) >> 16);  // RNE
}
__device__ __forceinline__ unsigned short bfc(float f) {
    __hip_bfloat16 h = __float2bfloat16(f);
    union { __hip_bfloat16 h; unsigned short u; } v; v.h = h;
    return v.u;
}

typedef __attribute__((address_space(1))) const unsigned int as1_cu32;
typedef __attribute__((address_space(3))) unsigned int as3_u32;
__device__ __forceinline__ void gload16(const void* g, void* l) {
    __builtin_amdgcn_global_load_lds((as1_cu32*)g, (as3_u32*)l, 16, 0, 0);
}

// ============ prepass: W (f32 [k][n] 512x512) -> Wt (bf16 [n][k]) ============
__global__ __launch_bounds__(256) void kprep(const float* __restrict__ Wq,
                                             const float* __restrict__ Wk,
                                             const float* __restrict__ Wv,
                                             const float* __restrict__ Wo,
                                             unsigned short* __restrict__ Wt) {
    const float* src = blockIdx.z == 0 ? Wq : blockIdx.z == 1 ? Wk
                     : blockIdx.z == 2 ? Wv : Wo;
    unsigned short* dst = Wt + (size_t)blockIdx.z * DM * DM;
    __shared__ float t[64][65];
    int c = threadIdx.x & 63, r4 = threadIdx.x >> 6;
    int kb = blockIdx.x * 64, nb = blockIdx.y * 64;
    for (int i = 0; i < 16; i++) {
        int r = r4 * 16 + i;
        t[r][c] = src[(size_t)(kb + r) * DM + nb + c];
    }
    __syncthreads();
    for (int i = 0; i < 16; i++) {
        int r = r4 * 16 + i;
        dst[(size_t)(nb + r) * DM + kb + c] = f2bf(t[c][r]);
    }
}

// ============ kernel 1: weight-stationary fused pad+cvt+QKV projection =======
// Best-measured config (R11): 512 blocks, TPB=13, 8 waves; wave holds
// B[32 n][512 k] bf16 in 128 VGPRs (loaded once per block). A tile
// [32 m][512 k]: f32 reg-prefetch -> cvt -> swizzled LDS (32 KB single
// buffer, 2 barriers/tile). Grid pairing: n-halves of a work unit are 8
// blockIdx apart (same XCD under round-robin) -> shared-A L2 hits.
__global__ __launch_bounds__(512, 2) void kproj(const float* __restrict__ q,
                                                const float* __restrict__ k,
                                                const float* __restrict__ v,
                                                const unsigned short* __restrict__ Wt,
                                                const float* __restrict__ bq,
                                                const float* __restrict__ bk,
                                                const float* __restrict__ bv,
                                                unsigned short* __restrict__ Qb,
                                                unsigned short* __restrict__ Kb,
                                                unsigned short* __restrict__ VT) {
    int L = blockIdx.x;                          // 0..511
    int P = (L >> 4) * 8 + (L & 7);              // work unit
    int nhalf = (L >> 3) & 1;
    if (P >= 12 * NBI) return;
    int z = P / NBI, bi = P % NBI;
    int ten = z >> 2, b = z & 3;
    int t0 = bi * TPB;
    int tcnt = NTILES - t0; if (tcnt > TPB) tcnt = TPB;
    if (tcnt <= 0) return;

    const float* A = (ten == 0 ? q : ten == 1 ? k : v) + (size_t)b * SEQ * DM;
    const unsigned short* Wten = Wt + (size_t)ten * DM * DM;
    const float* bias = ten == 0 ? bq : ten == 1 ? bk : bv;
    float scale = ten == 0 ? 0.07715167498104595f : 1.f;   // 1/sqrt(168)

    __shared__ __align__(16) char lds[32768];    // [32 rows][1024 B] bf16 swz

    int tid = threadIdx.x, lane = tid & 63, w = tid >> 6;
    int l15 = lane & 15, g = lane >> 4;
    int n0w = nhalf * 256 + w * 32;              // wave's 32-col slice
    int h = n0w >> 6;
    int hb2 = h * BATCH + b;

    // ---- B slice into registers (once per block)
    short8 Breg[2][16];
#pragma unroll
    for (int nf = 0; nf < 2; nf++)
#pragma unroll
        for (int s5 = 0; s5 < 16; s5++)
            Breg[nf][s5] = *(const short8*)(Wten +
                (size_t)(n0w + nf * 16 + l15) * DM + s5 * 32 + g * 8);

    float bias0 = bias[n0w + l15];
    float bias1 = bias[n0w + 16 + l15];

    int srow = tid >> 4, sc = tid & 15;
    int woff = srow * 1024 + ((sc ^ (srow & 7)) << 4);

    auto loadreg = [&](float4v (&d)[8], int tt) {
        int p = tt * 32 + srow; if (p > KP - 1) p = KP - 1;
        int ar = p - PAD_; ar = ar < 0 ? 0 : (ar > SEQ - 1 ? SEQ - 1 : ar);
        const float* s = A + (size_t)ar * DM + sc * 8;
#pragma unroll
        for (int j = 0; j < 4; j++) {
            d[2 * j]     = *(const float4v*)(s + j * 128);
            d[2 * j + 1] = *(const float4v*)(s + j * 128 + 4);
        }
    };

    float4v a[8];
    loadreg(a, t0);

    for (int ti = 0; ti < tcnt; ti++) {
        int tt = t0 + ti;
#pragma unroll
        for (int j = 0; j < 4; j++) {
            float4v f0 = a[2 * j], f1 = a[2 * j + 1];
            short8 h0;
            h0[0] = (short)bfc(f0.x); h0[1] = (short)bfc(f0.y);
            h0[2] = (short)bfc(f0.z); h0[3] = (short)bfc(f0.w);
            h0[4] = (short)bfc(f1.x); h0[5] = (short)bfc(f1.y);
            h0[6] = (short)bfc(f1.z); h0[7] = (short)bfc(f1.w);
            *(short8*)(lds + woff + j * 256) = h0;
        }
        if (ti + 1 < tcnt) loadreg(a, tt + 1);
        __builtin_amdgcn_sched_barrier(0);
        asm volatile("s_waitcnt lgkmcnt(0)" ::: "memory");
        __builtin_amdgcn_s_barrier();
        __builtin_amdgcn_sched_barrier(0);

        float4v acc[2][2];
#pragma unroll
        for (int mf = 0; mf < 2; mf++)
#pragma unroll
            for (int nf = 0; nf < 2; nf++) {
                float4v zz = {0.f, 0.f, 0.f, 0.f}; acc[mf][nf] = zz;
            }
#pragma unroll
        for (int s5 = 0; s5 < 16; s5++) {
            short8 afr[2];
#pragma unroll
            for (int mf = 0; mf < 2; mf++) {
                int row = mf * 16 + l15, c = s5 * 4 + g;
                afr[mf] = *(const short8*)(lds + row * 1024 + ((c ^ (row & 7)) << 4));
            }
#pragma unroll
            for (int mf = 0; mf < 2; mf++)
#pragma unroll
                for (int nf = 0; nf < 2; nf++)
                    acc[mf][nf] = MFMA16(afr[mf], Breg[nf][s5], acc[mf][nf], 0, 0, 0);
        }
        __builtin_amdgcn_s_barrier();            // reads done -> buf reusable
        __builtin_amdgcn_sched_barrier(0);

        int p0 = tt * 32;
        if (ten <= 1) {
            unsigned short* O = ten == 0 ? Qb : Kb;
#pragma unroll
            for (int nf = 0; nf < 2; nf++) {
                float bval = nf ? bias1 : bias0;
                int d = ((n0w + nf * 16) & 63) + l15;
                unsigned short* op = O + (size_t)hb2 * KP * 64 + d;
#pragma unroll
                for (int mf = 0; mf < 2; mf++) {
                    float4v vv = acc[mf][nf];
#pragma unroll
                    for (int r = 0; r < 4; r++) {
                        int p = p0 + mf * 16 + g * 4 + r;
                        if (p < KP)
                            op[(size_t)p * 64] = f2bf((vv[r] + bval) * scale);
                    }
                }
            }
        } else {
#pragma unroll
            for (int nf = 0; nf < 2; nf++) {
                float bval = nf ? bias1 : bias0;
                int d = ((n0w + nf * 16) & 63) + l15;
                unsigned short* base = VT + ((size_t)hb2 * 64 + d) * KP;
#pragma unroll
                for (int mf = 0; mf < 2; mf++) {
                    int p = p0 + mf * 16 + g * 4;
                    if (p <= KP - 4) {
                        float4v vv = acc[mf][nf];
                        ushort4v wv;
                        wv[0] = f2bf(vv.x + bval); wv[1] = f2bf(vv.y + bval);
                        wv[2] = f2bf(vv.z + bval); wv[3] = f2bf(vv.w + bval);
                        *(ushort4v*)(base + p) = wv;
                    }
                }
            }
        }
    }
}

// ============ kernel 2: windowed causal attention (44 KB LDS, 3 blocks/CU) ===
__global__ __launch_bounds__(384) void kattn(const unsigned short* __restrict__ Qb,
                                             const unsigned short* __restrict__ Kb,
                                             const unsigned short* __restrict__ VT,
                                             unsigned short* __restrict__ attn) {
    int win = blockIdx.x, hb = blockIdx.y;
    int h = hb >> 2, b = hb & 3;
    const unsigned short* Qg = Qb + (size_t)hb * KP * 64;
    const unsigned short* Kg = Kb + (size_t)hb * KP * 64;
    const unsigned short* Vt = VT + (size_t)hb * 64 * KP;
    int p0 = win * STEP_;

    __shared__ __align__(16) char lds[45056];

    int tid = threadIdx.x, lane = tid & 63, f = tid >> 6;
    int l15 = lane & 15, g = lane >> 4;

#pragma unroll
    for (int it = 0; it < 5; it++) {
        int base = it * 384 + f * 64;
        if (base < 768) {                       // Q chunks
            int c = base + lane;
            int qi = c >> 3, kg = (c & 7) ^ (qi & 7);
            gload16(Qg + (size_t)(p0 + PAD_ + qi) * 64 + kg * 8, lds + base * 16);
        } else if (base < 1792) {               // K chunks
            int c = base + lane - 768;
            int x = c >> 3, kg = (c & 7) ^ (x & 7);
            gload16(Kg + (size_t)(p0 + x) * 64 + kg * 8, lds + base * 16);
        }
    }
    for (int c = tid; c < 2048; c += 384) {
        int d = c >> 5, c2 = c & 31;
        ushort4v wv = *(const ushort4v*)(Vt + (size_t)d * KP + p0 + c2 * 4);
        int cx = c2 >> 1;
        *(ushort4v*)(lds + 28672 + d * 256 + (((cx ^ (d & 7)) << 4) | ((c2 & 1) * 8))) = wv;
    }
    __syncthreads();

    short8 bq2[2];
    {
        int r = f * 16 + l15;
#pragma unroll
        for (int ks = 0; ks < 2; ks++) {
            int kg = ks * 4 + g;
            bq2[ks] = *(const short8*)(lds + r * 128 + ((kg ^ (r & 7)) << 4));
        }
    }
    float4v st[8];
#pragma unroll
    for (int xf = 0; xf < 8; xf++) {
        float4v zz = {0.f,0.f,0.f,0.f}; st[xf] = zz;
#pragma unroll
        for (int ks = 0; ks < 2; ks++) {
            int r = xf * 16 + l15;
            int kg = ks * 4 + g;
            short8 a = *(const short8*)(lds + 12288 + r * 128 + ((kg ^ (r & 7)) << 4));
            st[xf] = MFMA16(a, bq2[ks], st[xf], 0, 0, 0);
        }
    }

    int w_abs = PAD_ + f * 16 + l15;
    int w_eff = w_abs > 125 ? 125 : w_abs;
    float mx = -1e30f;
#pragma unroll
    for (int xf = 0; xf < 8; xf++)
#pragma unroll
        for (int r = 0; r < 4; r++) {
            int x = xf * 16 + g * 4 + r;
            float vv = st[xf][r];
            if (x > w_eff) vv = -1e30f;
            st[xf][r] = vv;
            mx = fmaxf(mx, vv);
        }
    mx = fmaxf(mx, __shfl_xor(mx, 16));
    mx = fmaxf(mx, __shfl_xor(mx, 32));
    float s = 0.f;
#pragma unroll
    for (int xf = 0; xf < 8; xf++)
#pragma unroll
        for (int r = 0; r < 4; r++) {
            float e = __expf(st[xf][r] - mx);
            st[xf][r] = e;
            s += e;
        }
    s += __shfl_xor(s, 16);
    s += __shfl_xor(s, 32);
    float inv = 1.f / s;

    __syncthreads();   // Ql/Kl reads done -> Pl may clobber [0,24576)

    {
        int qi = f * 16 + l15;
#pragma unroll
        for (int xf = 0; xf < 8; xf++) {
            ushort4v pw;
#pragma unroll
            for (int r = 0; r < 4; r++) pw[r] = f2bf(st[xf][r] * inv);
            int xc = 2 * xf + (g >> 1);
            *(ushort4v*)(lds + qi * 256 + ((xc ^ (qi & 7)) << 4) + (g & 1) * 8) = pw;
        }
    }
    asm volatile("s_waitcnt lgkmcnt(0)" ::: "memory");
    __builtin_amdgcn_sched_barrier(0);

    float4v pv[4];
#pragma unroll
    for (int j = 0; j < 4; j++) { float4v zz = {0.f,0.f,0.f,0.f}; pv[j] = zz; }
    int qi = f * 16 + l15;
#pragma unroll
    for (int g2 = 0; g2 < 4; g2++) {
        int xc = g2 * 4 + g;
        short8 a = *(const short8*)(lds + qi * 256 + ((xc ^ (qi & 7)) << 4));
#pragma unroll
        for (int j = 0; j < 4; j++) {
            int d = j * 16 + l15;
            short8 bvv = *(const short8*)(lds + 28672 + d * 256 + ((xc ^ (d & 7)) << 4));
            pv[j] = MFMA16(a, bvv, pv[j], 0, 0, 0);
        }
    }

    __syncthreads();   // PV reads of P done -> Ol may clobber [0,12288)

    unsigned short* Ol = (unsigned short*)lds;
#pragma unroll
    for (int j = 0; j < 4; j++) {
        int d = j * 16 + l15;
#pragma unroll
        for (int r = 0; r < 4; r++) {
            int qq = f * 16 + g * 4 + r;
            int byte = qq * 128 + ((((d >> 3) ^ (qq & 7))) << 4) + (d & 7) * 2;
            *(unsigned short*)((char*)Ol + byte) = f2bf(pv[j][r]);
        }
    }
    __syncthreads();
    for (int c = tid; c < 672; c += 384) {
        int qq = c >> 3, ch = c & 7;
        short8 hv = *(const short8*)((char*)Ol + qq * 128 + ((ch ^ (qq & 7)) << 4));
        size_t off = ((size_t)(b * SEQ + win * STEP_ + qq) * DM) + h * 64 + ch * 8;
        *(short8*)(attn + off) = hv;
    }
}

// ============ kernel 3: weight-stationary output projection ==================
__global__ __launch_bounds__(512, 2) void kout(const unsigned short* __restrict__ Ab,
                                               const unsigned short* __restrict__ W,
                                               const float* __restrict__ bias,
                                               float* __restrict__ Out) {
    int L = blockIdx.x;                          // 0..703
    int P = (L >> 4) * 8 + (L & 7);
    int nhalf = (L >> 3) & 1;
    if (P >= OT_NBI) return;
    int t0 = P * OT_TPB;

    __shared__ __align__(16) char lds[32768];

    int tid = threadIdx.x, lane = tid & 63, w = tid >> 6;
    int l15 = lane & 15, g = lane >> 4;
    int n0w = nhalf * 256 + w * 32;

    short8 Breg[2][16];
#pragma unroll
    for (int nf = 0; nf < 2; nf++)
#pragma unroll
        for (int s5 = 0; s5 < 16; s5++)
            Breg[nf][s5] = *(const short8*)(W +
                (size_t)(n0w + nf * 16 + l15) * DM + s5 * 32 + g * 8);

    float bias0 = bias[n0w + l15];
    float bias1 = bias[n0w + 16 + l15];

    int srow = tid >> 4, sc = tid & 15;

    auto loadreg = [&](short8 (&d)[4], int tt) {
        const unsigned short* s = Ab + (size_t)(tt * 32 + srow) * DM;
#pragma unroll
        for (int j = 0; j < 4; j++)
            d[j] = *(const short8*)(s + (sc + j * 16) * 8);
    };

    short8 a[4];
    loadreg(a, t0);

    for (int ti = 0; ti < OT_TPB; ti++) {
        int tt = t0 + ti;
#pragma unroll
        for (int j = 0; j < 4; j++)
            *(short8*)(lds + srow * 1024 +
                       (((sc + j * 16) ^ (srow & 7)) << 4)) = a[j];
        if (ti + 1 < OT_TPB) loadreg(a, tt + 1);
        __builtin_amdgcn_sched_barrier(0);
        asm volatile("s_waitcnt lgkmcnt(0)" ::: "memory");
        __builtin_amdgcn_s_barrier();
        __builtin_amdgcn_sched_barrier(0);

        float4v acc[2][2];
#pragma unroll
        for (int mf = 0; mf < 2; mf++)
#pragma unroll
            for (int nf = 0; nf < 2; nf++) {
                float4v zz = {0.f, 0.f, 0.f, 0.f}; acc[mf][nf] = zz;
            }
#pragma unroll
        for (int s5 = 0; s5 < 16; s5++) {
            short8 afr[2];
#pragma unroll
            for (int mf = 0; mf < 2; mf++) {
                int row = mf * 16 + l15, c = s5 * 4 + g;
                afr[mf] = *(const short8*)(lds + row * 1024 + ((c ^ (row & 7)) << 4));
            }
#pragma unroll
            for (int mf = 0; mf < 2; mf++)
#pragma unroll
                for (int nf = 0; nf < 2; nf++)
                    acc[mf][nf] = MFMA16(afr[mf], Breg[nf][s5], acc[mf][nf], 0, 0, 0);
        }
        __builtin_amdgcn_s_barrier();
        __builtin_amdgcn_sched_barrier(0);

        int p0 = tt * 32;
#pragma unroll
        for (int nf = 0; nf < 2; nf++) {
            float bval = nf ? bias1 : bias0;
            int n = n0w + nf * 16 + l15;
#pragma unroll
            for (int mf = 0; mf < 2; mf++) {
                float4v vv = acc[mf][nf];
#pragma unroll
                for (int r = 0; r < 4; r++) {
                    int m = p0 + mf * 16 + g * 4 + r;
                    Out[(size_t)m * DM + n] = vv[r] + bval;
                }
            }
        }
    }
}

// ============ launch =========================================================
extern "C" void kernel_launch(void* const* d_in, const int* in_sizes, int n_in,
                              void* d_out, int out_size, void* d_ws, size_t ws_size,
                              hipStream_t stream) {
    const float* q  = (const float*)d_in[0];
    const float* k  = (const float*)d_in[1];
    const float* v  = (const float*)d_in[2];
    const float* Wq = (const float*)d_in[3];
    const float* bq = (const float*)d_in[4];
    const float* Wk = (const float*)d_in[5];
    const float* bk = (const float*)d_in[6];
    const float* Wv = (const float*)d_in[7];
    const float* bv = (const float*)d_in[8];
    const float* Wo = (const float*)d_in[9];
    const float* bo = (const float*)d_in[10];

    const size_t WT_ELEMS  = (size_t)4 * DM * DM;
    const size_t QKV_ELEMS = (size_t)32 * KP * 64;
    const size_t ATT_ELEMS = (size_t)MROWS * DM;
    size_t need = (WT_ELEMS + 3 * QKV_ELEMS + ATT_ELEMS) * 2;
    if (ws_size < need) return;

    unsigned short* Wt = (unsigned short*)d_ws;
    unsigned short* Qb = Wt + WT_ELEMS;
    unsigned short* Kb = Qb + QKV_ELEMS;
    unsigned short* VT = Kb + QKV_ELEMS;
    unsigned short* Ab = VT + QKV_ELEMS;

    kprep<<<dim3(8, 8, 4), dim3(256), 0, stream>>>(Wq, Wk, Wv, Wo, Wt);
    kproj<<<dim3(512), dim3(512), 0, stream>>>(q, k, v, Wt, bq, bk, bv,
                                               Qb, Kb, VT);
    kattn<<<dim3(NWIN, 32), dim3(384), 0, stream>>>(Qb, Kb, VT, Ab);
    kout<<<dim3(704), dim3(512), 0, stream>>>(Ab, Wt + 3 * DM * DM, bo,
                                              (float*)d_out);
}